// Round 1
// baseline (1076.422 us; speedup 1.0000x reference)
//
#include <hip/hip_runtime.h>
#include <hip/hip_bf16.h>
#include <math.h>

#define TTOK 8192
#define DM   1024
#define NE   8
#define FH   4096
#define ECAP 8192

typedef __attribute__((ext_vector_type(8))) short bf16x8;
typedef __attribute__((ext_vector_type(4))) float f32x4;

__device__ __forceinline__ unsigned short f2bf(float f) {
  union { float f; unsigned u; } v; v.f = f;
  unsigned r = v.u + 0x7fffu + ((v.u >> 16) & 1u);
  return (unsigned short)(r >> 16);
}

// async global->LDS, 16B per lane; LDS dst must be wave-uniform-base + lane*16
__device__ __forceinline__ void async16(const unsigned short* g, unsigned short* l) {
  __builtin_amdgcn_global_load_lds(
      (const __attribute__((address_space(1))) void*)g,
      (__attribute__((address_space(3))) void*)l, 16, 0, 0);
}

// exact-gelu via Abramowitz-Stegun 7.1.26 erf approx (|err| <= 1.5e-7)
__device__ __forceinline__ float gelu_erf(float v) {
  float x = v * 0.70710678118654752f;
  float ax = fabsf(x);
  float t = __frcp_rn(1.0f + 0.3275911f * ax);
  float poly = t * (0.254829592f + t * (-0.284496736f +
               t * (1.421413741f + t * (-1.453152027f + t * 1.061405429f))));
  float erfa = 1.0f - poly * __expf(-ax * ax);
  float erfx = copysignf(erfa, x);
  return 0.5f * v * (1.0f + erfx);
}

// ---------------- x -> bf16 ----------------
__global__ void cvt_x(const float* __restrict__ x, unsigned short* __restrict__ xb, int n4) {
  int id = blockIdx.x * 256 + threadIdx.x;
  if (id >= n4) return;
  float4 v = ((const float4*)x)[id];
  ushort4 o;
  o.x = f2bf(v.x); o.y = f2bf(v.y); o.z = f2bf(v.z); o.w = f2bf(v.w);
  ((ushort4*)xb)[id] = o;
}

// ---------------- fp32 [NE][R][Cc] -> bf16 [NE][Cc][R] (transpose+convert) ----
__global__ __launch_bounds__(256) void transpose_cvt(
    const float* __restrict__ src, unsigned short* __restrict__ dst, int R, int Cc) {
  __shared__ unsigned short t[64 * 72];
  int e = blockIdx.z;
  int c0 = blockIdx.x * 64, r0 = blockIdx.y * 64;
  int tid = threadIdx.x;
  const float* sp = src + (size_t)e * R * Cc;
  unsigned short* dp = dst + (size_t)e * R * Cc;
#pragma unroll
  for (int p = 0; p < 4; ++p) {
    int idx = p * 256 + tid;
    int row = idx >> 4;
    int c4 = (idx & 15) * 4;
    float4 v = *(const float4*)(sp + (size_t)(r0 + row) * Cc + c0 + c4);
    t[(c4 + 0) * 72 + row] = f2bf(v.x);
    t[(c4 + 1) * 72 + row] = f2bf(v.y);
    t[(c4 + 2) * 72 + row] = f2bf(v.z);
    t[(c4 + 3) * 72 + row] = f2bf(v.w);
  }
  __syncthreads();
#pragma unroll
  for (int p = 0; p < 4; ++p) {
    int idx = p * 256 + tid;
    int crow = idx >> 4;
    int r4 = (idx & 15) * 4;
    ushort4 o = *(ushort4*)(&t[crow * 72 + r4]);
    *(ushort4*)(dp + (size_t)(c0 + crow) * R + r0 + r4) = o;
  }
}

// ---------------- gating: softmax + top2 + bucket append ----------------
__global__ __launch_bounds__(256) void gate_kernel(
    const float* __restrict__ x, const float* __restrict__ wg,
    int* __restrict__ cnt, int* __restrict__ ent_tok, float* __restrict__ ent_w) {
  __shared__ float wls[NE * DM];
  int tid = threadIdx.x;
  for (int i = tid; i < NE * DM / 4; i += 256)
    ((float4*)wls)[i] = ((const float4*)wg)[i];
  __syncthreads();

  int wave = tid >> 6, lane = tid & 63;
  int t = blockIdx.x * 4 + wave;
  const float* xp = x + (size_t)t * DM;
  float acc[NE];
#pragma unroll
  for (int e = 0; e < NE; ++e) acc[e] = 0.f;
#pragma unroll
  for (int i = 0; i < 16; ++i) {
    float xv = xp[i * 64 + lane];
#pragma unroll
    for (int e = 0; e < NE; ++e) acc[e] += xv * wls[e * DM + i * 64 + lane];
  }
#pragma unroll
  for (int e = 0; e < NE; ++e) {
    float v = acc[e];
    for (int off = 32; off; off >>= 1) v += __shfl_xor(v, off, 64);
    acc[e] = v;
  }
  if (lane == 0) {
    float mx = acc[0];
#pragma unroll
    for (int e = 1; e < NE; ++e) mx = fmaxf(mx, acc[e]);
    float p[NE], s = 0.f;
#pragma unroll
    for (int e = 0; e < NE; ++e) { p[e] = __expf(acc[e] - mx); s += p[e]; }
    float inv = 1.f / s;
#pragma unroll
    for (int e = 0; e < NE; ++e) p[e] *= inv;
    int i0 = 0; float m0v = p[0];
#pragma unroll
    for (int e = 1; e < NE; ++e) if (p[e] > m0v) { m0v = p[e]; i0 = e; }
    int i1 = -1; float m1v = -1.f;
#pragma unroll
    for (int e = 0; e < NE; ++e) if (e != i0 && p[e] > m1v) { m1v = p[e]; i1 = e; }
    int pos0 = atomicAdd(&cnt[i0], 1);
    ent_tok[i0 * ECAP + pos0] = t * 2;
    ent_w[i0 * ECAP + pos0] = m0v;
    int pos1 = atomicAdd(&cnt[i1], 1);
    ent_tok[i1 * ECAP + pos1] = t * 2 + 1;
    ent_w[i1 * ECAP + pos1] = m1v;
  }
}

// ---------------- exclusive scan of expert counts ----------------
__global__ void scan_cnt(const int* __restrict__ cnt, int* __restrict__ base) {
  if (threadIdx.x == 0) {
    int s = 0;
    for (int e = 0; e < NE; ++e) { base[e] = s; s += cnt[e]; }
  }
}

// =====================================================================
// 8-phase 256x256 grouped GEMM (T2 swizzle + T3/T4 counted vmcnt + T5)
//   BM=BN=256, BK=64, 512 threads = 8 waves (2M x 4N), per-wave 128x64
//   LDS 128 KiB: sA/sB [buf][half][128*64] bf16
//   LDS swizzle: linear gload_lds dest + inverse-swizzled global source,
//   read col_byte ^= ((row&7)<<4)  -> conflict-free ds_read_b128
// =====================================================================

#define LDS_BAR __builtin_amdgcn_s_barrier()
#define WAITLGKM asm volatile("s_waitcnt lgkmcnt(0)" ::: "memory")
#define WAITVM4  asm volatile("s_waitcnt vmcnt(4)" ::: "memory")
#define WAITVM0  asm volatile("s_waitcnt vmcnt(0)" ::: "memory")

#define LD_A8(imb)                                                                \
  _Pragma("unroll") for (int ii = 0; ii < 4; ++ii) {                              \
    af[ii][0] = *(const bf16x8*)(aBase + ((imb) + ii) * 2048 + rowbA + colb0);    \
    af[ii][1] = *(const bf16x8*)(aBase + ((imb) + ii) * 2048 + rowbA + colb1);    \
  }

#define LD_B4(inb)                                                                \
  _Pragma("unroll") for (int jj = 0; jj < 2; ++jj) {                              \
    bf[(inb) + jj][0] = *(const bf16x8*)(bBase + ((inb) + jj) * 2048 + rowbB + colb0); \
    bf[(inb) + jj][1] = *(const bf16x8*)(bBase + ((inb) + jj) * 2048 + rowbB + colb1); \
  }

#define MMAQ(imb, inb)                                                            \
  _Pragma("unroll") for (int ii = 0; ii < 4; ++ii)                                \
  _Pragma("unroll") for (int jj = 0; jj < 2; ++jj) {                              \
    acc[(imb) + ii][(inb) + jj] = __builtin_amdgcn_mfma_f32_16x16x32_bf16(        \
        af[ii][0], bf[(inb) + jj][0], acc[(imb) + ii][(inb) + jj], 0, 0, 0);      \
    acc[(imb) + ii][(inb) + jj] = __builtin_amdgcn_mfma_f32_16x16x32_bf16(        \
        af[ii][1], bf[(inb) + jj][1], acc[(imb) + ii][(inb) + jj], 0, 0, 0);      \
  }

#define STG_A(b, h, k0) {                                                         \
    async16(pA[(h) * 2 + 0] + (k0), &sA[(b)][(h)][tid * 8]);                      \
    async16(pA[(h) * 2 + 1] + (k0), &sA[(b)][(h)][4096 + tid * 8]);               \
  }
#define STG_B(b, h, k0) {                                                         \
    async16(pB[(h) * 2 + 0] + (k0), &sB[(b)][(h)][tid * 8]);                      \
    async16(pB[(h) * 2 + 1] + (k0), &sB[(b)][(h)][4096 + tid * 8]);               \
  }

// GELU=true : A = gather(xb via ent_tok), out = gelu(acc+bias) -> bf16 hout
// GELU=false: A = hbuf rows (be+i),       out = w*(acc+bias)   -> f32 yout
template <int KTOT, int NTOT, bool GELU>
__global__ __launch_bounds__(512, 2) void moe_gemm8(
    const unsigned short* __restrict__ Asrc, const unsigned short* __restrict__ Bsrc,
    const float* __restrict__ bias, const int* __restrict__ cnt,
    const int* __restrict__ base, const int* __restrict__ ent_tok,
    const float* __restrict__ ent_w, unsigned short* __restrict__ hout,
    float* __restrict__ yout) {
  const int bid = blockIdx.x;
  const int e = bid & 7;              // XCD pin
  const int j = bid >> 3;
  const int mt = j & 31;              // m inner -> neighbors share B panel
  const int nt = j >> 5;
  const int C = cnt[e];
  const int m0 = mt * 256;
  if (m0 >= C) return;
  const int n0 = nt * 256;
  const int be = base[e];
  const int tid = threadIdx.x;
  const int lane = tid & 63, wave = tid >> 6;
  const int wm = wave >> 2;           // 0..1  (M half)
  const int wn = wave & 3;            // 0..3  (N quarter)
  const int q = lane >> 4, l16 = lane & 15;

  __shared__ unsigned short sA[2][2][8192];  // [buf][half][128*64]
  __shared__ unsigned short sB[2][2][8192];

  // ---- staging source pointers (pre-swizzled global column) ----
  // linear LDS pos (row, (tid&7)*16B) receives global col ((tid&7)^(row&7))*16B
  const int xorc = (((tid & 7) ^ ((tid >> 3) & 7)) << 3);  // elements
  const unsigned short* pA[4];
  const unsigned short* pB[4];
#pragma unroll
  for (int h = 0; h < 2; ++h)
#pragma unroll
    for (int l = 0; l < 2; ++l) {
      const int R = h * 128 + l * 64 + (tid >> 3);
      int i = m0 + R; if (i >= C) i = C - 1;
      size_t arow;
      if (GELU) arow = (size_t)(ent_tok[e * ECAP + i] >> 1);
      else      arow = (size_t)(be + i);
      pA[h * 2 + l] = Asrc + arow * (size_t)KTOT + xorc;
      pB[h * 2 + l] = Bsrc + ((size_t)e * NTOT + n0 + R) * (size_t)KTOT + xorc;
    }

  // ---- LDS read offsets (swizzled) ----
  const int rowbA = l16 * 128;
  const int rowbB = ((wn & 1) * 64 + l16) * 128;
  const int colb0 = (q * 16) ^ ((l16 & 7) << 4);
  const int colb1 = colb0 ^ 64;

  f32x4 acc[8][4];
#pragma unroll
  for (int i = 0; i < 8; ++i)
#pragma unroll
    for (int jj = 0; jj < 4; ++jj) acc[i][jj] = (f32x4){0.f, 0.f, 0.f, 0.f};
  bf16x8 af[4][2], bf[4][2];

  // ---- prologue: K0 fully + B halves of K1; leave 2 half-tiles in flight ----
  STG_A(0, 0, 0) STG_A(0, 1, 0)
  STG_B(0, 0, 0) STG_B(0, 1, 0)
  STG_B(1, 0, 64) STG_B(1, 1, 64)
  WAITVM4;
  LDS_BAR;

  constexpr int NT = KTOT / 64;
#pragma unroll 1
  for (int t = 0; t < NT; ++t) {
    const int buf = t & 1;
    const char* aBase = (const char*)&sA[buf][wm][0];
    const char* bBase = (const char*)&sB[buf][wn >> 1][0];
    const int kA = (t + 1) * 64;   // A half-tiles for K-tile t+1 -> buf^1
    const int kB = (t + 2) * 64;   // B half-tiles for K-tile t+2 -> buf

    // phase 1: Q(m0-3 x n0-1); stage A-half0(t+1)
    LD_A8(0) LD_B4(0)
    if (t + 1 < NT) { STG_A(buf ^ 1, 0, kA) }
    LDS_BAR; WAITLGKM;
    __builtin_amdgcn_s_setprio(1); MMAQ(0, 0) __builtin_amdgcn_s_setprio(0);
    LDS_BAR;

    // phase 2: Q(m0-3 x n2-3); stage A-half1(t+1). B(buf) fully read after here.
    LD_B4(2)
    if (t + 1 < NT) { STG_A(buf ^ 1, 1, kA) }
    LDS_BAR; WAITLGKM;
    __builtin_amdgcn_s_setprio(1); MMAQ(0, 2) __builtin_amdgcn_s_setprio(0);
    LDS_BAR;

    // phase 3: Q(m4-7 x n0-1); stage B-half0(t+2) into freed B(buf) region.
    LD_A8(4)
    if (t + 2 < NT) { STG_B(buf, 0, kB) }
    LDS_BAR; WAITLGKM;
    __builtin_amdgcn_s_setprio(1); MMAQ(4, 0) __builtin_amdgcn_s_setprio(0);
    LDS_BAR;

    // phase 4: Q(m4-7 x n2-3); stage B-half1(t+2); counted vmcnt (never 0
    // in steady state: exactly the 2 B(t+2) half-tiles stay in flight).
    if (t + 2 < NT) { STG_B(buf, 1, kB) }
    __builtin_amdgcn_s_setprio(1); MMAQ(4, 2) __builtin_amdgcn_s_setprio(0);
    if (t + 2 < NT) { WAITVM4; } else { WAITVM0; }  // tail: A(t+1) must drain
    LDS_BAR;
  }

  // ---- epilogue ----
  float bl[4];
#pragma unroll
  for (int in2 = 0; in2 < 4; ++in2)
    bl[in2] = bias[(size_t)e * NTOT + n0 + wn * 64 + in2 * 16 + l16];

#pragma unroll
  for (int im = 0; im < 8; ++im)
#pragma unroll
    for (int rr = 0; rr < 4; ++rr) {
      const int gm = m0 + wm * 128 + im * 16 + q * 4 + rr;
      if (gm >= C) continue;
      if (GELU) {
        const size_t bas = (size_t)(be + gm) * NTOT + n0;
#pragma unroll
        for (int in2 = 0; in2 < 4; ++in2) {
          const int n = wn * 64 + in2 * 16 + l16;
          hout[bas + n] = f2bf(gelu_erf(acc[im][in2][rr] + bl[in2]));
        }
      } else {
        const int rowid = ent_tok[e * ECAP + gm];
        const float w = ent_w[e * ECAP + gm];
        const size_t bas = (size_t)rowid * NTOT + n0;
#pragma unroll
        for (int in2 = 0; in2 < 4; ++in2) {
          const int n = wn * 64 + in2 * 16 + l16;
          yout[bas + n] = w * (acc[im][in2][rr] + bl[in2]);
        }
      }
    }
}

// ---------------- combine: out[t] = y[2t] + y[2t+1] ----------------
__global__ void combine_k(const float* __restrict__ y, float* __restrict__ out, int n4) {
  int id = blockIdx.x * 256 + threadIdx.x;
  if (id >= n4) return;
  int t = id >> 8;   // 256 float4 per 1024-elem row
  int c = id & 255;
  float4 a = ((const float4*)y)[((size_t)t * 2) * 256 + c];
  float4 b = ((const float4*)y)[((size_t)t * 2 + 1) * 256 + c];
  float4 o = {a.x + b.x, a.y + b.y, a.z + b.z, a.w + b.w};
  ((float4*)out)[id] = o;
}

extern "C" void kernel_launch(void* const* d_in, const int* in_sizes, int n_in,
                              void* d_out, int out_size, void* d_ws, size_t ws_size,
                              hipStream_t stream) {
  const float* x  = (const float*)d_in[0];
  const float* wg = (const float*)d_in[1];
  const float* W1 = (const float*)d_in[2];
  const float* b1 = (const float*)d_in[3];
  const float* W2 = (const float*)d_in[4];
  const float* b2 = (const float*)d_in[5];
  float* out = (float*)d_out;

  char* ws = (char*)d_ws;
  size_t off = 0;
  unsigned short* xb = (unsigned short*)(ws + off); off += (size_t)TTOK * DM * 2;        // 16 MB
  int* cnt = (int*)(ws + off); off += 128;
  int* base = (int*)(ws + off); off += 128;
  int* ent_tok = (int*)(ws + off); off += (size_t)NE * ECAP * 4;                         // 256 KB
  float* ent_w = (float*)(ws + off); off += (size_t)NE * ECAP * 4;                       // 256 KB
  unsigned short* W1T = (unsigned short*)(ws + off); off += (size_t)NE * DM * FH * 2;    // 64 MB
  unsigned short* W2T = (unsigned short*)(ws + off); off += (size_t)NE * FH * DM * 2;    // 64 MB
  unsigned short* hbuf = (unsigned short*)(ws + off); off += (size_t)TTOK * 2 * FH * 2;  // 128 MB
  // ybuf overlays W1T: W1T is dead after gemm1, regenerated next launch before gemm1
  float* ybuf = (float*)W1T;                                                             // 64 MB

  hipMemsetAsync(cnt, 0, 128, stream);
  cvt_x<<<TTOK * DM / 4 / 256, 256, 0, stream>>>(x, xb, TTOK * DM / 4);
  gate_kernel<<<TTOK / 4, 256, 0, stream>>>(x, wg, cnt, ent_tok, ent_w);
  scan_cnt<<<1, 64, 0, stream>>>(cnt, base);
  dim3 t1(FH / 64, DM / 64, NE);
  transpose_cvt<<<t1, 256, 0, stream>>>(W1, W1T, DM, FH);
  dim3 t2(DM / 64, FH / 64, NE);
  transpose_cvt<<<t2, 256, 0, stream>>>(W2, W2T, FH, DM);
  // GEMM1: 8 experts x 32 m-tiles x 16 n-tiles = 4096 blocks (early-exit on m0>=C)
  moe_gemm8<DM, FH, true><<<NE * 32 * (FH / 256), 512, 0, stream>>>(
      xb, W1T, b1, cnt, base, ent_tok, ent_w, hbuf, nullptr);
  // GEMM2: 8 experts x 32 m-tiles x 4 n-tiles = 1024 blocks
  moe_gemm8<FH, DM, false><<<NE * 32 * (DM / 256), 512, 0, stream>>>(
      hbuf, W2T, b2, cnt, base, ent_tok, ent_w, nullptr, ybuf);
  combine_k<<<TTOK * DM / 4 / 256, 256, 0, stream>>>(ybuf, out, TTOK * DM / 4);
}